// Round 4
// baseline (598.434 us; speedup 1.0000x reference)
//
#include <hip/hip_runtime.h>
#include <hip/hip_bf16.h>

// MHA: B=4 L=2048 D=1024 H=16 DH=64, causal.
// Round 4: DTYPE-PROOF. Device-side sniffer detects whether inputs are bf16
// or f32 from x's bit patterns; canonicalization kernels convert everything
// to bf16 (biases to f32). Output dtype follows the flag. Pipeline itself is
// round-3's deterministic-staging MFMA GEMM + fused flash attention.

typedef __bf16 bf16;
typedef __bf16 bf16x8 __attribute__((ext_vector_type(8)));
typedef float f32x4 __attribute__((ext_vector_type(4)));

#define DEV static __device__ __forceinline__

constexpr int B = 4, L = 2048, D = 1024, H = 16, DH = 64;
constexpr int BL = B * L;                      // 8192
constexpr int GM = 8192, GN = 1024, GK = 1024; // all 4 GEMMs share this shape
constexpr int BKg = 64;                        // GEMM K-tile

DEV f32x4 mfma(bf16x8 a, bf16x8 b, f32x4 c) {
  return __builtin_amdgcn_mfma_f32_16x16x32_bf16(a, b, c, 0, 0, 0);
}

DEV float scrub(float v) { return (v == v) ? v : 0.f; }

// ---------- dtype sniff ----------
// Even-index u16s of x: bf16 storage -> normal values, sane exponent field;
// f32 storage -> low mantissa halves, uniform bits -> ~9% sane. flag=1: bf16.
__global__ void sniff_k(const unsigned short* __restrict__ xr, int* flag) {
  __shared__ int cnt;
  if (threadIdx.x == 0) cnt = 0;
  __syncthreads();
  int local = 0;
  for (int i = threadIdx.x; i < 4096; i += 64) {
    const unsigned short u = xr[2 * i];
    const int e = (u >> 7) & 0xFF;            // exponent field of bf16
    if (e >= 0x70 && e <= 0x85) local++;      // 2^-15 .. 2^6
  }
  atomicAdd(&cnt, local);
  __syncthreads();
  if (threadIdx.x == 0) *flag = (cnt > 2048) ? 1 : 0;
}

// ---------- canonicalize x -> bf16 ----------
__global__ __launch_bounds__(256) void cvt_x_k(const void* __restrict__ src,
                                               bf16* __restrict__ dst,
                                               const int* __restrict__ flag, int n) {
  const bool isbf = (*flag != 0);
  const int stride = gridDim.x * blockDim.x * 8;
  for (int idx = (blockIdx.x * blockDim.x + threadIdx.x) * 8; idx < n; idx += stride) {
    bf16x8 o;
    if (isbf) {
      bf16x8 v = *(const bf16x8*)((const bf16*)src + idx);
      #pragma unroll
      for (int j = 0; j < 8; ++j) o[j] = (bf16)scrub((float)v[j]);
    } else {
      const float* s = (const float*)src + idx;
      #pragma unroll
      for (int j = 0; j < 8; ++j) o[j] = (bf16)scrub(s[j]);
    }
    *(bf16x8*)&dst[idx] = o;
  }
}

// ---------- transpose + canonicalize weight: dst[n][k] = src[k][n] ----------
__global__ __launch_bounds__(256) void wtrans_cvt_k(const void* __restrict__ src,
                                                    bf16* __restrict__ dst,
                                                    const int* __restrict__ flag) {
  __shared__ bf16 t[32][33];
  const bool isbf = (*flag != 0);
  const int bx = blockIdx.x * 32, by = blockIdx.y * 32;
  const int tx = threadIdx.x & 31, ty = threadIdx.x >> 5;
  for (int i = ty; i < 32; i += 8) {
    const size_t off = (size_t)(by + i) * D + bx + tx;
    const float v = isbf ? (float)((const bf16*)src)[off] : ((const float*)src)[off];
    t[i][tx] = (bf16)scrub(v);
  }
  __syncthreads();
  for (int i = ty; i < 32; i += 8)
    dst[(size_t)(bx + i) * D + by + tx] = t[tx][i];
}

// ---------- canonicalize bias -> f32 ----------
__global__ void cvt_bias_k(const void* __restrict__ src, float* __restrict__ dst,
                           const int* __restrict__ flag) {
  const bool isbf = (*flag != 0);
  const int i = blockIdx.x * blockDim.x + threadIdx.x;
  if (i < D) dst[i] = scrub(isbf ? (float)((const bf16*)src)[i] : ((const float*)src)[i]);
}

// ---------- GEMM: C[M,N] = A[M,K] @ Bt[N,K]^T + bias ----------
// 128x128 tile, 4 waves 2x2, wave does 64x64 via 4x4 16x16x32 MFMA frags.
// final_out=0: write bf16. final_out=1: dtype per flag (f32 if inputs were f32).
__global__ __launch_bounds__(256) void gemm_bt_k(const bf16* __restrict__ A,
                                                 const bf16* __restrict__ Bt,
                                                 const float* __restrict__ bias,
                                                 void* __restrict__ C,
                                                 const int* __restrict__ flag,
                                                 int final_out) {
  __shared__ __align__(16) bf16 As[128 * BKg];
  __shared__ __align__(16) bf16 Bs[128 * BKg];
  const bool wbf = (!final_out) || (*flag != 0);
  const int m0 = blockIdx.x * 128, n0 = blockIdx.y * 128;
  const int tid = threadIdx.x, wave = tid >> 6, lane = tid & 63;
  const int wr = wave >> 1, wc = wave & 1;
  const int quad = lane >> 4, l16 = lane & 15;

  f32x4 acc[4][4] = {};

  for (int k0 = 0; k0 < GK; k0 += BKg) {
    #pragma unroll
    for (int i = 0; i < 4; ++i) {
      const int o = tid * 8 + i * 2048;       // [0,8192), 16B aligned
      const int row = o >> 6, col = o & 63;   // row-major [128][64]
      *(bf16x8*)&As[o] = *(const bf16x8*)&A[(size_t)(m0 + row) * GK + k0 + col];
      *(bf16x8*)&Bs[o] = *(const bf16x8*)&Bt[(size_t)(n0 + row) * GK + k0 + col];
    }
    __syncthreads();
    #pragma unroll
    for (int kk = 0; kk < BKg; kk += 32) {
      bf16x8 af[4], bfr[4];
      #pragma unroll
      for (int i = 0; i < 4; ++i)
        af[i] = *(const bf16x8*)&As[(wr * 64 + i * 16 + l16) * BKg + kk + quad * 8];
      #pragma unroll
      for (int i = 0; i < 4; ++i)
        bfr[i] = *(const bf16x8*)&Bs[(wc * 64 + i * 16 + l16) * BKg + kk + quad * 8];
      #pragma unroll
      for (int mi = 0; mi < 4; ++mi)
        #pragma unroll
        for (int ni = 0; ni < 4; ++ni)
          acc[mi][ni] = mfma(af[mi], bfr[ni], acc[mi][ni]);
    }
    __syncthreads();
  }

  // epilogue: C-layout col=lane&15, row=quad*4+r (m89-verified)
  bf16* Cb = (bf16*)C;
  float* Cf = (float*)C;
  #pragma unroll
  for (int ni = 0; ni < 4; ++ni) {
    const int col = n0 + wc * 64 + ni * 16 + l16;
    const float bv = bias[col];
    #pragma unroll
    for (int mi = 0; mi < 4; ++mi)
      #pragma unroll
      for (int r = 0; r < 4; ++r) {
        const int row = m0 + wr * 64 + mi * 16 + quad * 4 + r;
        const float v = acc[mi][ni][r] + bv;
        if (wbf) Cb[(size_t)row * GN + col] = (bf16)v;
        else     Cf[(size_t)row * GN + col] = v;
      }
  }
}

// ---------- fused causal flash attention (round-3, unchanged) ----------
__global__ __launch_bounds__(256) void attn_k(bf16* QO,
                                              const bf16* __restrict__ K,
                                              const bf16* __restrict__ V) {
  __shared__ __align__(16) bf16 Ks[64 * DH];
  __shared__ __align__(16) bf16 Vt[DH * 64];
  __shared__ __align__(16) bf16 Ps[4][16 * 64];

  const int qt = blockIdx.x;
  const int bh = blockIdx.y;
  const int b = bh >> 4, h = bh & 15;
  const int tid = threadIdx.x, wave = tid >> 6, lane = tid & 63;
  const int quad = lane >> 4, l16 = lane & 15;

  bf16* Qb = QO + (size_t)b * L * D + h * DH;
  const bf16* Kb = K + (size_t)b * L * D + h * DH;
  const bf16* Vb = V + (size_t)b * L * D + h * DH;

  const int qrow = qt * 64 + wave * 16 + l16;
  bf16x8 qf0 = *(const bf16x8*)(Qb + (size_t)qrow * D + quad * 8);
  bf16x8 qf1 = *(const bf16x8*)(Qb + (size_t)qrow * D + 32 + quad * 8);
  #pragma unroll
  for (int i = 0; i < 8; ++i) {
    qf0[i] = (bf16)((float)qf0[i] * 0.125f);
    qf1[i] = (bf16)((float)qf1[i] * 0.125f);
  }

  float m_run[4], l_run[4];
  f32x4 o_acc[4] = {};
  #pragma unroll
  for (int r = 0; r < 4; ++r) { m_run[r] = -INFINITY; l_run[r] = 0.f; }

  const int vkey = tid >> 2, vd0 = (tid & 3) * 16;

  for (int kt = 0; kt <= qt; ++kt) {
    #pragma unroll
    for (int i = 0; i < 2; ++i) {
      const int o = tid * 8 + i * 2048;
      const int row = o >> 6, col = o & 63;
      *(bf16x8*)&Ks[o] = *(const bf16x8*)&Kb[(size_t)(kt * 64 + row) * D + col];
    }
    {
      const bf16* g = Vb + (size_t)(kt * 64 + vkey) * D + vd0;
      #pragma unroll
      for (int j = 0; j < 16; ++j)
        Vt[(vd0 + j) * 64 + vkey] = g[j];
    }
    __syncthreads();

    f32x4 s[4];
    #pragma unroll
    for (int nb = 0; nb < 4; ++nb) {
      bf16x8 k0 = *(const bf16x8*)&Ks[(nb * 16 + l16) * DH + quad * 8];
      bf16x8 k1 = *(const bf16x8*)&Ks[(nb * 16 + l16) * DH + 32 + quad * 8];
      f32x4 a = {};
      a = mfma(qf0, k0, a);
      a = mfma(qf1, k1, a);
      s[nb] = a;
    }

    if (kt == qt) {
      #pragma unroll
      for (int nb = 0; nb < 4; ++nb) {
        const int key = nb * 16 + l16;
        #pragma unroll
        for (int r = 0; r < 4; ++r)
          if (key > wave * 16 + quad * 4 + r) s[nb][r] = -1e30f;
      }
    }

    bf16* Pw = &Ps[wave][0];
    #pragma unroll
    for (int r = 0; r < 4; ++r) {
      float mx = fmaxf(fmaxf(s[0][r], s[1][r]), fmaxf(s[2][r], s[3][r]));
      #pragma unroll
      for (int off = 8; off >= 1; off >>= 1) mx = fmaxf(mx, __shfl_xor(mx, off, 64));
      const float mn = fmaxf(m_run[r], mx);
      const float alpha = __expf(m_run[r] - mn);
      m_run[r] = mn;
      float sum = 0.f;
      #pragma unroll
      for (int nb = 0; nb < 4; ++nb) {
        const float p = __expf(s[nb][r] - mn);
        sum += p;
        Pw[(quad * 4 + r) * 64 + nb * 16 + l16] = (bf16)p;
      }
      #pragma unroll
      for (int off = 8; off >= 1; off >>= 1) sum += __shfl_xor(sum, off, 64);
      l_run[r] = l_run[r] * alpha + sum;
      #pragma unroll
      for (int db = 0; db < 4; ++db) o_acc[db][r] *= alpha;
    }
    __syncthreads();

    bf16x8 p0 = *(const bf16x8*)&Pw[l16 * 64 + quad * 8];
    bf16x8 p1 = *(const bf16x8*)&Pw[l16 * 64 + 32 + quad * 8];
    #pragma unroll
    for (int db = 0; db < 4; ++db) {
      bf16x8 v0 = *(const bf16x8*)&Vt[(db * 16 + l16) * 64 + quad * 8];
      bf16x8 v1 = *(const bf16x8*)&Vt[(db * 16 + l16) * 64 + 32 + quad * 8];
      o_acc[db] = mfma(p0, v0, o_acc[db]);
      o_acc[db] = mfma(p1, v1, o_acc[db]);
    }
    __syncthreads();
  }

  #pragma unroll
  for (int r = 0; r < 4; ++r) {
    const float inv = 1.f / l_run[r];
    const int row = qt * 64 + wave * 16 + quad * 4 + r;
    #pragma unroll
    for (int db = 0; db < 4; ++db)
      Qb[(size_t)row * D + db * 16 + l16] = (bf16)(o_acc[db][r] * inv);
  }
}

extern "C" void kernel_launch(void* const* d_in, const int* in_sizes, int n_in,
                              void* d_out, int out_size, void* d_ws, size_t ws_size,
                              hipStream_t stream) {
  const void* x  = d_in[0];
  const void* Wq = d_in[1];
  const void* bq = d_in[2];
  const void* Wk = d_in[3];
  const void* bk = d_in[4];
  const void* Wv = d_in[5];
  const void* bv = d_in[6];
  const void* Wo = d_in[7];
  const void* bo = d_in[8];
  // d_in[9] = causal mask, analytic

  // ws layout (bytes): [flag int][pad to 4096][xc 16M][4x WT 2M][4x bias 4K]
  //                    [Q 16M][K 16M][V 16M]  total ~72 MiB
  int* flag = (int*)d_ws;
  char* p = (char*)d_ws + 4096;
  bf16* xc  = (bf16*)p;                 p += (size_t)BL * D * 2;
  bf16* WqT = (bf16*)p;                 p += (size_t)D * D * 2;
  bf16* WkT = (bf16*)p;                 p += (size_t)D * D * 2;
  bf16* WvT = (bf16*)p;                 p += (size_t)D * D * 2;
  bf16* WoT = (bf16*)p;                 p += (size_t)D * D * 2;
  float* bqc = (float*)p;               p += D * 4;
  float* bkc = (float*)p;               p += D * 4;
  float* bvc = (float*)p;               p += D * 4;
  float* boc = (float*)p;               p += D * 4;
  bf16* Qb  = (bf16*)p;                 p += (size_t)BL * D * 2;  // O aliases Q
  bf16* Kb  = (bf16*)p;                 p += (size_t)BL * D * 2;
  bf16* Vb  = (bf16*)p;

  sniff_k<<<1, 64, 0, stream>>>((const unsigned short*)x, flag);

  cvt_x_k<<<1024, 256, 0, stream>>>(x, xc, flag, BL * D);
  dim3 tgrid(32, 32);
  wtrans_cvt_k<<<tgrid, 256, 0, stream>>>(Wq, WqT, flag);
  wtrans_cvt_k<<<tgrid, 256, 0, stream>>>(Wk, WkT, flag);
  wtrans_cvt_k<<<tgrid, 256, 0, stream>>>(Wv, WvT, flag);
  wtrans_cvt_k<<<tgrid, 256, 0, stream>>>(Wo, WoT, flag);
  cvt_bias_k<<<4, 256, 0, stream>>>(bq, bqc, flag);
  cvt_bias_k<<<4, 256, 0, stream>>>(bk, bkc, flag);
  cvt_bias_k<<<4, 256, 0, stream>>>(bv, bvc, flag);
  cvt_bias_k<<<4, 256, 0, stream>>>(bo, boc, flag);

  dim3 ggrid(GM / 128, GN / 128);
  gemm_bt_k<<<ggrid, 256, 0, stream>>>(xc, WqT, bqc, Qb, flag, 0);
  gemm_bt_k<<<ggrid, 256, 0, stream>>>(xc, WkT, bkc, Kb, flag, 0);
  gemm_bt_k<<<ggrid, 256, 0, stream>>>(xc, WvT, bvc, Vb, flag, 0);

  attn_k<<<dim3(L / 64, B * H), 256, 0, stream>>>(Qb, Kb, Vb);

  gemm_bt_k<<<ggrid, 256, 0, stream>>>(Qb, WoT, boc, d_out, flag, 1);
}

// Round 5
// 407.610 us; speedup vs baseline: 1.4682x; 1.4682x over previous
//
#include <hip/hip_runtime.h>
#include <hip/hip_bf16.h>

// MHA: B=4 L=2048 D=1024 H=16 DH=64, causal. Inputs are f32 (detected R4);
// dtype-proof sniffer retained. Round 5: attention overhaul — pre-transposed
// V (coalesced staging), LPT block order, 2 barriers/tile, async
// global_load_lds staging in GEMM + attention.

typedef __bf16 bf16;
typedef __bf16 bf16x8 __attribute__((ext_vector_type(8)));
typedef float f32x4 __attribute__((ext_vector_type(4)));

#define DEV static __device__ __forceinline__

constexpr int B = 4, L = 2048, D = 1024, H = 16, DH = 64;
constexpr int BL = B * L;                      // 8192
constexpr int GM = 8192, GN = 1024, GK = 1024; // all 4 GEMMs share this shape
constexpr int BKg = 64;                        // GEMM K-tile

typedef __attribute__((address_space(1))) const void* gptr1;
typedef __attribute__((address_space(3))) void* lptr3;

DEV void load_lds16(const bf16* g, bf16* l) {
  // async global->LDS, 16B/lane; LDS dest = wave-uniform base + lane*16.
  __builtin_amdgcn_global_load_lds((gptr1)g, (lptr3)l, 16, 0, 0);
}

DEV f32x4 mfma(bf16x8 a, bf16x8 b, f32x4 c) {
  return __builtin_amdgcn_mfma_f32_16x16x32_bf16(a, b, c, 0, 0, 0);
}

DEV float scrub(float v) { return (v == v) ? v : 0.f; }

// ---------- dtype sniff (flag=1: bf16 storage, 0: f32) ----------
__global__ void sniff_k(const unsigned short* __restrict__ xr, int* flag) {
  __shared__ int cnt;
  if (threadIdx.x == 0) cnt = 0;
  __syncthreads();
  int local = 0;
  for (int i = threadIdx.x; i < 4096; i += 64) {
    const unsigned short u = xr[2 * i];
    const int e = (u >> 7) & 0xFF;
    if (e >= 0x70 && e <= 0x85) local++;
  }
  atomicAdd(&cnt, local);
  __syncthreads();
  if (threadIdx.x == 0) *flag = (cnt > 2048) ? 1 : 0;
}

// ---------- canonicalize x -> bf16 ----------
__global__ __launch_bounds__(256) void cvt_x_k(const void* __restrict__ src,
                                               bf16* __restrict__ dst,
                                               const int* __restrict__ flag, int n) {
  const bool isbf = (*flag != 0);
  const int stride = gridDim.x * blockDim.x * 8;
  for (int idx = (blockIdx.x * blockDim.x + threadIdx.x) * 8; idx < n; idx += stride) {
    bf16x8 o;
    if (isbf) {
      bf16x8 v = *(const bf16x8*)((const bf16*)src + idx);
      #pragma unroll
      for (int j = 0; j < 8; ++j) o[j] = (bf16)scrub((float)v[j]);
    } else {
      const float* s = (const float*)src + idx;
      #pragma unroll
      for (int j = 0; j < 8; ++j) o[j] = (bf16)scrub(s[j]);
    }
    *(bf16x8*)&dst[idx] = o;
  }
}

// ---------- transpose + canonicalize weight: dst[n][k] = src[k][n] ----------
__global__ __launch_bounds__(256) void wtrans_cvt_k(const void* __restrict__ src,
                                                    bf16* __restrict__ dst,
                                                    const int* __restrict__ flag) {
  __shared__ bf16 t[32][33];
  const bool isbf = (*flag != 0);
  const int bx = blockIdx.x * 32, by = blockIdx.y * 32;
  const int tx = threadIdx.x & 31, ty = threadIdx.x >> 5;
  for (int i = ty; i < 32; i += 8) {
    const size_t off = (size_t)(by + i) * D + bx + tx;
    const float v = isbf ? (float)((const bf16*)src)[off] : ((const float*)src)[off];
    t[i][tx] = (bf16)scrub(v);
  }
  __syncthreads();
  for (int i = ty; i < 32; i += 8)
    dst[(size_t)(bx + i) * D + by + tx] = t[tx][i];
}

// ---------- per-head V transpose: VT[bh][d][l] = V[(b,l)][h*64+d] ----------
// grid (L/64, BH). 64l x 64d tile per block, LDS-tiled, coalesced both sides.
__global__ __launch_bounds__(256) void vtrans_k(const bf16* __restrict__ V,
                                                bf16* __restrict__ VT) {
  __shared__ __align__(16) bf16 t[64 * 72]; // stride 72 breaks write conflicts
  const int l0 = blockIdx.x * 64, bh = blockIdx.y;
  const int b = bh >> 4, h = bh & 15;
  const int tid = threadIdx.x;
  #pragma unroll
  for (int i = 0; i < 2; ++i) {
    const int o = tid * 8 + i * 2048;
    const int lrow = o >> 6, dcol = o & 63;
    *(bf16x8*)&t[lrow * 72 + dcol] =
        *(const bf16x8*)&V[(size_t)(b * L + l0 + lrow) * D + h * 64 + dcol];
  }
  __syncthreads();
  const int d = tid >> 2, lg = (tid & 3) * 16;
  bf16x8 o0, o1;
  #pragma unroll
  for (int j = 0; j < 8; ++j) o0[j] = t[(lg + j) * 72 + d];
  #pragma unroll
  for (int j = 0; j < 8; ++j) o1[j] = t[(lg + 8 + j) * 72 + d];
  bf16* dst = VT + ((size_t)bh * DH + d) * L + l0 + lg;
  *(bf16x8*)dst = o0;
  *(bf16x8*)(dst + 8) = o1;
}

// ---------- GEMM: C[M,N] = A[M,K] @ Bt[N,K]^T + bias ----------
// 128x128 tile, 4 waves 2x2, wave 64x64 via 4x4 16x16x32 MFMA; async staging.
__global__ __launch_bounds__(256) void gemm_bt_k(const bf16* __restrict__ A,
                                                 const bf16* __restrict__ Bt,
                                                 const void* __restrict__ bias,
                                                 void* __restrict__ C,
                                                 const int* __restrict__ flag,
                                                 int final_out) {
  __shared__ __align__(16) bf16 As[128 * BKg];
  __shared__ __align__(16) bf16 Bs[128 * BKg];
  const bool isbf = (*flag != 0);
  const bool wbf = (!final_out) || isbf;
  const int m0 = blockIdx.x * 128, n0 = blockIdx.y * 128;
  const int tid = threadIdx.x, wave = tid >> 6, lane = tid & 63;
  const int wr = wave >> 1, wc = wave & 1;
  const int quad = lane >> 4, l16 = lane & 15;
  const int srow = lane >> 3, scol = (lane & 7) * 8; // chunk: 8 rows x 64 cols

  f32x4 acc[4][4] = {};

  for (int k0 = 0; k0 < GK; k0 += BKg) {
    for (int c = wave; c < 16; c += 4) { // 16 x 1KB chunks per 16KB tile
      load_lds16(A  + (size_t)(m0 + c * 8 + srow) * GK + k0 + scol, &As[c * 512]);
      load_lds16(Bt + (size_t)(n0 + c * 8 + srow) * GK + k0 + scol, &Bs[c * 512]);
    }
    __syncthreads();
    #pragma unroll
    for (int kk = 0; kk < BKg; kk += 32) {
      bf16x8 af[4], bfr[4];
      #pragma unroll
      for (int i = 0; i < 4; ++i)
        af[i] = *(const bf16x8*)&As[(wr * 64 + i * 16 + l16) * BKg + kk + quad * 8];
      #pragma unroll
      for (int i = 0; i < 4; ++i)
        bfr[i] = *(const bf16x8*)&Bs[(wc * 64 + i * 16 + l16) * BKg + kk + quad * 8];
      #pragma unroll
      for (int mi = 0; mi < 4; ++mi)
        #pragma unroll
        for (int ni = 0; ni < 4; ++ni)
          acc[mi][ni] = mfma(af[mi], bfr[ni], acc[mi][ni]);
    }
    __syncthreads();
  }

  bf16* Cb = (bf16*)C;
  float* Cf = (float*)C;
  #pragma unroll
  for (int ni = 0; ni < 4; ++ni) {
    const int col = n0 + wc * 64 + ni * 16 + l16;
    const float bv = isbf ? (float)((const bf16*)bias)[col] : ((const float*)bias)[col];
    #pragma unroll
    for (int mi = 0; mi < 4; ++mi)
      #pragma unroll
      for (int r = 0; r < 4; ++r) {
        const int row = m0 + wr * 64 + mi * 16 + quad * 4 + r;
        const float v = acc[mi][ni][r] + bv;
        if (wbf) Cb[(size_t)row * GN + col] = (bf16)v;
        else     Cf[(size_t)row * GN + col] = v;
      }
  }
}

// ---------- fused causal flash attention v2 ----------
// 1-D grid, LPT order: qt = 31 - bx/64 (heaviest first), bh = bx%64.
// K [BL][D]; VT [bh][64][L] pre-transposed. O overwrites Q in place.
__global__ __launch_bounds__(256) void attn_k(bf16* QO,
                                              const bf16* __restrict__ K,
                                              const bf16* __restrict__ VT) {
  __shared__ __align__(16) bf16 Ks[64 * DH];    // [key][d] 8KB
  __shared__ __align__(16) bf16 Vt[DH * 64];    // [d][key] 8KB
  __shared__ __align__(16) bf16 Ps[4][16 * 64]; // per-wave P 8KB

  const int bx = blockIdx.x;
  const int qt = (L / 64 - 1) - (bx >> 6);
  const int bh = bx & 63;
  const int b = bh >> 4, h = bh & 15;
  const int tid = threadIdx.x, wave = tid >> 6, lane = tid & 63;
  const int quad = lane >> 4, l16 = lane & 15;
  const int srow = lane >> 3, scol = (lane & 7) * 8;

  bf16* Qb = QO + (size_t)b * L * D + h * DH;
  const bf16* Kb = K + (size_t)b * L * D + h * DH;
  const bf16* VTg = VT + (size_t)bh * DH * L; // [d][l]

  // Q A-frags, pre-scaled by 1/sqrt(DH)=0.125 (exact pow2)
  const int qrow = qt * 64 + wave * 16 + l16;
  bf16x8 qf0 = *(const bf16x8*)(Qb + (size_t)qrow * D + quad * 8);
  bf16x8 qf1 = *(const bf16x8*)(Qb + (size_t)qrow * D + 32 + quad * 8);
  #pragma unroll
  for (int i = 0; i < 8; ++i) {
    qf0[i] = (bf16)((float)qf0[i] * 0.125f);
    qf1[i] = (bf16)((float)qf1[i] * 0.125f);
  }

  float m_run[4], l_run[4];
  f32x4 o_acc[4] = {};
  #pragma unroll
  for (int r = 0; r < 4; ++r) { m_run[r] = -INFINITY; l_run[r] = 0.f; }

  for (int kt = 0; kt <= qt; ++kt) {
    // stage K [64key][64d] + VT [64d][64key], 8 x 1KB chunks each, coalesced
    for (int c = wave; c < 8; c += 4) {
      load_lds16(Kb  + (size_t)(kt * 64 + c * 8 + srow) * D + scol, &Ks[c * 512]);
      load_lds16(VTg + (size_t)(c * 8 + srow) * L + kt * 64 + scol, &Vt[c * 512]);
    }
    __syncthreads();

    // S = (Q/8) @ K^T
    f32x4 s[4];
    #pragma unroll
    for (int nb = 0; nb < 4; ++nb) {
      bf16x8 k0 = *(const bf16x8*)&Ks[(nb * 16 + l16) * DH + quad * 8];
      bf16x8 k1 = *(const bf16x8*)&Ks[(nb * 16 + l16) * DH + 32 + quad * 8];
      f32x4 a = {};
      a = mfma(qf0, k0, a);
      a = mfma(qf1, k1, a);
      s[nb] = a;
    }

    if (kt == qt) { // diagonal-tile causal mask
      #pragma unroll
      for (int nb = 0; nb < 4; ++nb) {
        const int key = nb * 16 + l16;
        #pragma unroll
        for (int r = 0; r < 4; ++r)
          if (key > wave * 16 + quad * 4 + r) s[nb][r] = -1e30f;
      }
    }

    // online softmax; Ps is wave-private -> no block barrier needed before PV
    bf16* Pw = &Ps[wave][0];
    #pragma unroll
    for (int r = 0; r < 4; ++r) {
      float mx = fmaxf(fmaxf(s[0][r], s[1][r]), fmaxf(s[2][r], s[3][r]));
      #pragma unroll
      for (int off = 8; off >= 1; off >>= 1) mx = fmaxf(mx, __shfl_xor(mx, off, 64));
      const float mn = fmaxf(m_run[r], mx);
      const float alpha = __expf(m_run[r] - mn);
      m_run[r] = mn;
      float sum = 0.f;
      #pragma unroll
      for (int nb = 0; nb < 4; ++nb) {
        const float p = __expf(s[nb][r] - mn);
        sum += p;
        Pw[(quad * 4 + r) * 64 + nb * 16 + l16] = (bf16)p;
      }
      #pragma unroll
      for (int off = 8; off >= 1; off >>= 1) sum += __shfl_xor(sum, off, 64);
      l_run[r] = l_run[r] * alpha + sum;
      #pragma unroll
      for (int db = 0; db < 4; ++db) o_acc[db][r] *= alpha;
    }

    // O += P @ V
    bf16x8 p0 = *(const bf16x8*)&Pw[l16 * 64 + quad * 8];
    bf16x8 p1 = *(const bf16x8*)&Pw[l16 * 64 + 32 + quad * 8];
    #pragma unroll
    for (int db = 0; db < 4; ++db) {
      bf16x8 v0 = *(const bf16x8*)&Vt[(db * 16 + l16) * 64 + quad * 8];
      bf16x8 v1 = *(const bf16x8*)&Vt[(db * 16 + l16) * 64 + 32 + quad * 8];
      o_acc[db] = mfma(p0, v0, o_acc[db]);
      o_acc[db] = mfma(p1, v1, o_acc[db]);
    }
    __syncthreads(); // protect Ks/Vt before next tile's staging
  }

  #pragma unroll
  for (int r = 0; r < 4; ++r) {
    const float inv = 1.f / l_run[r];
    const int row = qt * 64 + wave * 16 + quad * 4 + r;
    #pragma unroll
    for (int db = 0; db < 4; ++db)
      Qb[(size_t)row * D + db * 16 + l16] = (bf16)(o_acc[db][r] * inv);
  }
}

extern "C" void kernel_launch(void* const* d_in, const int* in_sizes, int n_in,
                              void* d_out, int out_size, void* d_ws, size_t ws_size,
                              hipStream_t stream) {
  const void* x  = d_in[0];
  const void* Wq = d_in[1];
  const void* bq = d_in[2];
  const void* Wk = d_in[3];
  const void* bk = d_in[4];
  const void* Wv = d_in[5];
  const void* bv = d_in[6];
  const void* Wo = d_in[7];
  const void* bo = d_in[8];
  // d_in[9] = causal mask, analytic

  // ws: [flag pad 4096][xc 16M (VT aliases after QKV GEMMs)][4x WT 2M]
  //     [Q/O 16M][K 16M][V 16M]  total ~72 MiB
  int* flag = (int*)d_ws;
  char* p = (char*)d_ws + 4096;
  bf16* xc  = (bf16*)p;                 p += (size_t)BL * D * 2;
  bf16* WqT = (bf16*)p;                 p += (size_t)D * D * 2;
  bf16* WkT = (bf16*)p;                 p += (size_t)D * D * 2;
  bf16* WvT = (bf16*)p;                 p += (size_t)D * D * 2;
  bf16* WoT = (bf16*)p;                 p += (size_t)D * D * 2;
  bf16* Qb  = (bf16*)p;                 p += (size_t)BL * D * 2; // O aliases Q
  bf16* Kb  = (bf16*)p;                 p += (size_t)BL * D * 2;
  bf16* Vb  = (bf16*)p;
  bf16* VTb = xc; // xc dead after the 3 QKV GEMMs; reuse for V^T

  sniff_k<<<1, 64, 0, stream>>>((const unsigned short*)x, flag);

  cvt_x_k<<<1024, 256, 0, stream>>>(x, xc, flag, BL * D);
  dim3 tgrid(32, 32);
  wtrans_cvt_k<<<tgrid, 256, 0, stream>>>(Wq, WqT, flag);
  wtrans_cvt_k<<<tgrid, 256, 0, stream>>>(Wk, WkT, flag);
  wtrans_cvt_k<<<tgrid, 256, 0, stream>>>(Wv, WvT, flag);
  wtrans_cvt_k<<<tgrid, 256, 0, stream>>>(Wo, WoT, flag);

  dim3 ggrid(GM / 128, GN / 128);
  gemm_bt_k<<<ggrid, 256, 0, stream>>>(xc, WqT, bq, Qb, flag, 0);
  gemm_bt_k<<<ggrid, 256, 0, stream>>>(xc, WkT, bk, Kb, flag, 0);
  gemm_bt_k<<<ggrid, 256, 0, stream>>>(xc, WvT, bv, Vb, flag, 0);

  vtrans_k<<<dim3(L / 64, B * H), 256, 0, stream>>>(Vb, VTb);

  attn_k<<<dim3((L / 64) * B * H), 256, 0, stream>>>(Qb, Kb, VTb);

  gemm_bt_k<<<ggrid, 256, 0, stream>>>(Qb, WoT, bo, d_out, flag, 1);
}

// Round 6
// 357.250 us; speedup vs baseline: 1.6751x; 1.1410x over previous
//
#include <hip/hip_runtime.h>
#include <hip/hip_bf16.h>

// MHA: B=4 L=2048 D=1024 H=16 DH=64, causal. Inputs f32 (sniffed; dtype-proof).
// Round 6: kill LDS bank conflicts. XOR-swizzled K/V/A/B tile layout
// (compatible with global_load_lds's fixed base+lane*16 landing) + padded P.

typedef __bf16 bf16;
typedef __bf16 bf16x8 __attribute__((ext_vector_type(8)));
typedef float f32x4 __attribute__((ext_vector_type(4)));

#define DEV static __device__ __forceinline__

constexpr int B = 4, L = 2048, D = 1024, H = 16, DH = 64;
constexpr int BL = B * L;                      // 8192
constexpr int GM = 8192, GN = 1024, GK = 1024; // all 4 GEMMs share this shape
constexpr int BKg = 64;                        // GEMM K-tile
constexpr int PST = 72;                        // padded P row stride (elements)

typedef __attribute__((address_space(1))) const void* gptr1;
typedef __attribute__((address_space(3))) void* lptr3;

DEV void load_lds16(const bf16* g, bf16* l) {
  // async global->LDS, 16B/lane; LDS dest = wave-uniform base + lane*16.
  __builtin_amdgcn_global_load_lds((gptr1)g, (lptr3)l, 16, 0, 0);
}

DEV f32x4 mfma(bf16x8 a, bf16x8 b, f32x4 c) {
  return __builtin_amdgcn_mfma_f32_16x16x32_bf16(a, b, c, 0, 0, 0);
}

DEV float scrub(float v) { return (v == v) ? v : 0.f; }

// XOR-swizzle: LDS slot s of tile-row r holds column-chunk (s ^ (r&7)).
// Stagers read global chunk (lane&7)^(lane>>3) so the fixed landing slot
// (lane&7) of local row (lane>>3) receives the right chunk. Readers index
// slot (chunk ^ (row&7)). Breaks the row-stride-128B 16-way bank aliasing.

// ---------- dtype sniff (flag=1: bf16 storage, 0: f32) ----------
__global__ void sniff_k(const unsigned short* __restrict__ xr, int* flag) {
  __shared__ int cnt;
  if (threadIdx.x == 0) cnt = 0;
  __syncthreads();
  int local = 0;
  for (int i = threadIdx.x; i < 4096; i += 64) {
    const unsigned short u = xr[2 * i];
    const int e = (u >> 7) & 0xFF;
    if (e >= 0x70 && e <= 0x85) local++;
  }
  atomicAdd(&cnt, local);
  __syncthreads();
  if (threadIdx.x == 0) *flag = (cnt > 2048) ? 1 : 0;
}

// ---------- canonicalize x -> bf16 ----------
__global__ __launch_bounds__(256) void cvt_x_k(const void* __restrict__ src,
                                               bf16* __restrict__ dst,
                                               const int* __restrict__ flag, int n) {
  const bool isbf = (*flag != 0);
  const int stride = gridDim.x * blockDim.x * 8;
  for (int idx = (blockIdx.x * blockDim.x + threadIdx.x) * 8; idx < n; idx += stride) {
    bf16x8 o;
    if (isbf) {
      bf16x8 v = *(const bf16x8*)((const bf16*)src + idx);
      #pragma unroll
      for (int j = 0; j < 8; ++j) o[j] = (bf16)scrub((float)v[j]);
    } else {
      const float* s = (const float*)src + idx;
      #pragma unroll
      for (int j = 0; j < 8; ++j) o[j] = (bf16)scrub(s[j]);
    }
    *(bf16x8*)&dst[idx] = o;
  }
}

// ---------- transpose + canonicalize weight: dst[n][k] = src[k][n] ----------
__global__ __launch_bounds__(256) void wtrans_cvt_k(const void* __restrict__ src,
                                                    bf16* __restrict__ dst,
                                                    const int* __restrict__ flag) {
  __shared__ bf16 t[32][33];
  const bool isbf = (*flag != 0);
  const int bx = blockIdx.x * 32, by = blockIdx.y * 32;
  const int tx = threadIdx.x & 31, ty = threadIdx.x >> 5;
  for (int i = ty; i < 32; i += 8) {
    const size_t off = (size_t)(by + i) * D + bx + tx;
    const float v = isbf ? (float)((const bf16*)src)[off] : ((const float*)src)[off];
    t[i][tx] = (bf16)scrub(v);
  }
  __syncthreads();
  for (int i = ty; i < 32; i += 8)
    dst[(size_t)(bx + i) * D + by + tx] = t[tx][i];
}

// ---------- per-head V transpose: VT[bh][d][l] = V[(b,l)][h*64+d] ----------
__global__ __launch_bounds__(256) void vtrans_k(const bf16* __restrict__ V,
                                                bf16* __restrict__ VT) {
  __shared__ __align__(16) bf16 t[64 * 72];
  const int l0 = blockIdx.x * 64, bh = blockIdx.y;
  const int b = bh >> 4, h = bh & 15;
  const int tid = threadIdx.x;
  #pragma unroll
  for (int i = 0; i < 2; ++i) {
    const int o = tid * 8 + i * 2048;
    const int lrow = o >> 6, dcol = o & 63;
    *(bf16x8*)&t[lrow * 72 + dcol] =
        *(const bf16x8*)&V[(size_t)(b * L + l0 + lrow) * D + h * 64 + dcol];
  }
  __syncthreads();
  const int d = tid >> 2, lg = (tid & 3) * 16;
  bf16x8 o0, o1;
  #pragma unroll
  for (int j = 0; j < 8; ++j) o0[j] = t[(lg + j) * 72 + d];
  #pragma unroll
  for (int j = 0; j < 8; ++j) o1[j] = t[(lg + 8 + j) * 72 + d];
  bf16* dst = VT + ((size_t)bh * DH + d) * L + l0 + lg;
  *(bf16x8*)dst = o0;
  *(bf16x8*)(dst + 8) = o1;
}

// ---------- GEMM: C[M,N] = A[M,K] @ Bt[N,K]^T + bias ----------
// 128x128 tile, 4 waves 2x2, wave 64x64 via 4x4 16x16x32 MFMA.
// Async swizzled staging; swizzled frag reads (conflict-free b128).
__global__ __launch_bounds__(256) void gemm_bt_k(const bf16* __restrict__ A,
                                                 const bf16* __restrict__ Bt,
                                                 const void* __restrict__ bias,
                                                 void* __restrict__ C,
                                                 const int* __restrict__ flag,
                                                 int final_out) {
  __shared__ __align__(16) bf16 As[128 * BKg];
  __shared__ __align__(16) bf16 Bs[128 * BKg];
  const bool isbf = (*flag != 0);
  const bool wbf = (!final_out) || isbf;
  const int m0 = blockIdx.x * 128, n0 = blockIdx.y * 128;
  const int tid = threadIdx.x, wave = tid >> 6, lane = tid & 63;
  const int wr = wave >> 1, wc = wave & 1;
  const int quad = lane >> 4, l16 = lane & 15;
  const int srow = lane >> 3;
  const int scol = ((lane ^ srow) & 7) * 8;       // swizzled staging column
  const int l7 = l16 & 7;
  const int s0 = ((quad ^ l7) * 8);               // swizzled read slot, kk=0
  const int s1 = s0 ^ 32;                         // kk=32 (chunk | 4)

  f32x4 acc[4][4] = {};

  for (int k0 = 0; k0 < GK; k0 += BKg) {
    for (int c = wave; c < 16; c += 4) { // 16 x 1KB chunks per 16KB tile
      load_lds16(A  + (size_t)(m0 + c * 8 + srow) * GK + k0 + scol, &As[c * 512]);
      load_lds16(Bt + (size_t)(n0 + c * 8 + srow) * GK + k0 + scol, &Bs[c * 512]);
    }
    __syncthreads();
    #pragma unroll
    for (int kk = 0; kk < BKg; kk += 32) {
      const int sk = kk ? s1 : s0;
      bf16x8 af[4], bfr[4];
      #pragma unroll
      for (int i = 0; i < 4; ++i)
        af[i] = *(const bf16x8*)&As[(wr * 64 + i * 16 + l16) * BKg + sk];
      #pragma unroll
      for (int i = 0; i < 4; ++i)
        bfr[i] = *(const bf16x8*)&Bs[(wc * 64 + i * 16 + l16) * BKg + sk];
      #pragma unroll
      for (int mi = 0; mi < 4; ++mi)
        #pragma unroll
        for (int ni = 0; ni < 4; ++ni)
          acc[mi][ni] = mfma(af[mi], bfr[ni], acc[mi][ni]);
    }
    __syncthreads();
  }

  bf16* Cb = (bf16*)C;
  float* Cf = (float*)C;
  #pragma unroll
  for (int ni = 0; ni < 4; ++ni) {
    const int col = n0 + wc * 64 + ni * 16 + l16;
    const float bv = isbf ? (float)((const bf16*)bias)[col] : ((const float*)bias)[col];
    #pragma unroll
    for (int mi = 0; mi < 4; ++mi)
      #pragma unroll
      for (int r = 0; r < 4; ++r) {
        const int row = m0 + wr * 64 + mi * 16 + quad * 4 + r;
        const float v = acc[mi][ni][r] + bv;
        if (wbf) Cb[(size_t)row * GN + col] = (bf16)v;
        else     Cf[(size_t)row * GN + col] = v;
      }
  }
}

// ---------- fused causal flash attention v3 (swizzled LDS) ----------
// 1-D grid: qt = 31 - bx/64, bh = bx%64. K [BL][D]; VT [bh][64][L].
__global__ __launch_bounds__(256) void attn_k(bf16* QO,
                                              const bf16* __restrict__ K,
                                              const bf16* __restrict__ VT) {
  __shared__ __align__(16) bf16 Ks[64 * DH];       // swizzled [key][d]
  __shared__ __align__(16) bf16 Vt[DH * 64];       // swizzled [d][key]
  __shared__ __align__(16) bf16 Ps[4][16 * PST];   // padded per-wave P

  const int bx = blockIdx.x;
  const int qt = (L / 64 - 1) - (bx >> 6);
  const int bh = bx & 63;
  const int b = bh >> 4, h = bh & 15;
  const int tid = threadIdx.x, wave = tid >> 6, lane = tid & 63;
  const int quad = lane >> 4, l16 = lane & 15;
  const int srow = lane >> 3;
  const int scol = ((lane ^ srow) & 7) * 8;
  const int l7 = l16 & 7;
  const int s0 = ((quad ^ l7) * 8);
  const int s1 = s0 ^ 32;

  bf16* Qb = QO + (size_t)b * L * D + h * DH;
  const bf16* Kb = K + (size_t)b * L * D + h * DH;
  const bf16* VTg = VT + (size_t)bh * DH * L; // [d][l]

  // Q A-frags, pre-scaled by 1/sqrt(DH)=0.125 (exact pow2)
  const int qrow = qt * 64 + wave * 16 + l16;
  bf16x8 qf0 = *(const bf16x8*)(Qb + (size_t)qrow * D + quad * 8);
  bf16x8 qf1 = *(const bf16x8*)(Qb + (size_t)qrow * D + 32 + quad * 8);
  #pragma unroll
  for (int i = 0; i < 8; ++i) {
    qf0[i] = (bf16)((float)qf0[i] * 0.125f);
    qf1[i] = (bf16)((float)qf1[i] * 0.125f);
  }

  float m_run[4], l_run[4];
  f32x4 o_acc[4] = {};
  #pragma unroll
  for (int r = 0; r < 4; ++r) { m_run[r] = -INFINITY; l_run[r] = 0.f; }

  for (int kt = 0; kt <= qt; ++kt) {
    for (int c = wave; c < 8; c += 4) {
      load_lds16(Kb  + (size_t)(kt * 64 + c * 8 + srow) * D + scol, &Ks[c * 512]);
      load_lds16(VTg + (size_t)(c * 8 + srow) * L + kt * 64 + scol, &Vt[c * 512]);
    }
    __syncthreads();

    // S = (Q/8) @ K^T (swizzled K reads)
    f32x4 s[4];
    #pragma unroll
    for (int nb = 0; nb < 4; ++nb) {
      bf16x8 k0 = *(const bf16x8*)&Ks[(nb * 16 + l16) * DH + s0];
      bf16x8 k1 = *(const bf16x8*)&Ks[(nb * 16 + l16) * DH + s1];
      f32x4 a = {};
      a = mfma(qf0, k0, a);
      a = mfma(qf1, k1, a);
      s[nb] = a;
    }

    if (kt == qt) { // diagonal-tile causal mask
      #pragma unroll
      for (int nb = 0; nb < 4; ++nb) {
        const int key = nb * 16 + l16;
        #pragma unroll
        for (int r = 0; r < 4; ++r)
          if (key > wave * 16 + quad * 4 + r) s[nb][r] = -1e30f;
      }
    }

    // online softmax; Ps wave-private (no block barrier before PV)
    bf16* Pw = &Ps[wave][0];
    #pragma unroll
    for (int r = 0; r < 4; ++r) {
      float mx = fmaxf(fmaxf(s[0][r], s[1][r]), fmaxf(s[2][r], s[3][r]));
      #pragma unroll
      for (int off = 8; off >= 1; off >>= 1) mx = fmaxf(mx, __shfl_xor(mx, off, 64));
      const float mn = fmaxf(m_run[r], mx);
      const float alpha = __expf(m_run[r] - mn);
      m_run[r] = mn;
      float sum = 0.f;
      #pragma unroll
      for (int nb = 0; nb < 4; ++nb) {
        const float p = __expf(s[nb][r] - mn);
        sum += p;
        Pw[(quad * 4 + r) * PST + nb * 16 + l16] = (bf16)p;
      }
      #pragma unroll
      for (int off = 8; off >= 1; off >>= 1) sum += __shfl_xor(sum, off, 64);
      l_run[r] = l_run[r] * alpha + sum;
      #pragma unroll
      for (int db = 0; db < 4; ++db) o_acc[db][r] *= alpha;
    }

    // O += P @ V (padded P reads, swizzled V reads)
    bf16x8 p0 = *(const bf16x8*)&Pw[l16 * PST + quad * 8];
    bf16x8 p1 = *(const bf16x8*)&Pw[l16 * PST + 32 + quad * 8];
    #pragma unroll
    for (int db = 0; db < 4; ++db) {
      bf16x8 v0 = *(const bf16x8*)&Vt[(db * 16 + l16) * 64 + s0];
      bf16x8 v1 = *(const bf16x8*)&Vt[(db * 16 + l16) * 64 + s1];
      o_acc[db] = mfma(p0, v0, o_acc[db]);
      o_acc[db] = mfma(p1, v1, o_acc[db]);
    }
    __syncthreads(); // protect Ks/Vt before next tile's staging
  }

  #pragma unroll
  for (int r = 0; r < 4; ++r) {
    const float inv = 1.f / l_run[r];
    const int row = qt * 64 + wave * 16 + quad * 4 + r;
    #pragma unroll
    for (int db = 0; db < 4; ++db)
      Qb[(size_t)row * D + db * 16 + l16] = (bf16)(o_acc[db][r] * inv);
  }
}

extern "C" void kernel_launch(void* const* d_in, const int* in_sizes, int n_in,
                              void* d_out, int out_size, void* d_ws, size_t ws_size,
                              hipStream_t stream) {
  const void* x  = d_in[0];
  const void* Wq = d_in[1];
  const void* bq = d_in[2];
  const void* Wk = d_in[3];
  const void* bk = d_in[4];
  const void* Wv = d_in[5];
  const void* bv = d_in[6];
  const void* Wo = d_in[7];
  const void* bo = d_in[8];
  // d_in[9] = causal mask, analytic

  int* flag = (int*)d_ws;
  char* p = (char*)d_ws + 4096;
  bf16* xc  = (bf16*)p;                 p += (size_t)BL * D * 2;
  bf16* WqT = (bf16*)p;                 p += (size_t)D * D * 2;
  bf16* WkT = (bf16*)p;                 p += (size_t)D * D * 2;
  bf16* WvT = (bf16*)p;                 p += (size_t)D * D * 2;
  bf16* WoT = (bf16*)p;                 p += (size_t)D * D * 2;
  bf16* Qb  = (bf16*)p;                 p += (size_t)BL * D * 2; // O aliases Q
  bf16* Kb  = (bf16*)p;                 p += (size_t)BL * D * 2;
  bf16* Vb  = (bf16*)p;
  bf16* VTb = xc; // xc dead after the 3 QKV GEMMs; reuse for V^T

  sniff_k<<<1, 64, 0, stream>>>((const unsigned short*)x, flag);

  cvt_x_k<<<1024, 256, 0, stream>>>(x, xc, flag, BL * D);
  dim3 tgrid(32, 32);
  wtrans_cvt_k<<<tgrid, 256, 0, stream>>>(Wq, WqT, flag);
  wtrans_cvt_k<<<tgrid, 256, 0, stream>>>(Wk, WkT, flag);
  wtrans_cvt_k<<<tgrid, 256, 0, stream>>>(Wv, WvT, flag);
  wtrans_cvt_k<<<tgrid, 256, 0, stream>>>(Wo, WoT, flag);

  dim3 ggrid(GM / 128, GN / 128);
  gemm_bt_k<<<ggrid, 256, 0, stream>>>(xc, WqT, bq, Qb, flag, 0);
  gemm_bt_k<<<ggrid, 256, 0, stream>>>(xc, WkT, bk, Kb, flag, 0);
  gemm_bt_k<<<ggrid, 256, 0, stream>>>(xc, WvT, bv, Vb, flag, 0);

  vtrans_k<<<dim3(L / 64, B * H), 256, 0, stream>>>(Vb, VTb);

  attn_k<<<dim3((L / 64) * B * H), 256, 0, stream>>>(Qb, Kb, VTb);

  gemm_bt_k<<<ggrid, 256, 0, stream>>>(Qb, WoT, bo, d_out, flag, 1);
}

// Round 7
// 297.979 us; speedup vs baseline: 2.0083x; 1.1989x over previous
//
#include <hip/hip_runtime.h>
#include <hip/hip_bf16.h>

// MHA: B=4 L=2048 D=1024 H=16 DH=64, causal. Inputs f32 (sniffed; dtype-proof).
// Round 7: S^T attention (softmax state per-lane scalar, packed b64 P writes),
// fused QKV GEMM (one launch, N=3072), Q-scale folded into GEMM epilogue,
// fused 4-way weight transpose. Swizzled LDS throughout (R6-verified).

typedef __bf16 bf16;
typedef __bf16 bf16x4 __attribute__((ext_vector_type(4)));
typedef __bf16 bf16x8 __attribute__((ext_vector_type(8)));
typedef float f32x4 __attribute__((ext_vector_type(4)));

#define DEV static __device__ __forceinline__

constexpr int B = 4, L = 2048, D = 1024, H = 16, DH = 64;
constexpr int BL = B * L;                      // 8192
constexpr int GM = 8192, GK = 1024;
constexpr int BKg = 64;                        // GEMM K-tile
constexpr int PST = 72;                        // padded P row stride (elements)

typedef __attribute__((address_space(1))) const void* gptr1;
typedef __attribute__((address_space(3))) void* lptr3;

DEV void load_lds16(const bf16* g, bf16* l) {
  __builtin_amdgcn_global_load_lds((gptr1)g, (lptr3)l, 16, 0, 0);
}

DEV f32x4 mfma(bf16x8 a, bf16x8 b, f32x4 c) {
  return __builtin_amdgcn_mfma_f32_16x16x32_bf16(a, b, c, 0, 0, 0);
}

DEV float scrub(float v) { return (v == v) ? v : 0.f; }

// ---------- dtype sniff (flag=1: bf16 storage, 0: f32) ----------
__global__ void sniff_k(const unsigned short* __restrict__ xr, int* flag) {
  __shared__ int cnt;
  if (threadIdx.x == 0) cnt = 0;
  __syncthreads();
  int local = 0;
  for (int i = threadIdx.x; i < 4096; i += 64) {
    const unsigned short u = xr[2 * i];
    const int e = (u >> 7) & 0xFF;
    if (e >= 0x70 && e <= 0x85) local++;
  }
  atomicAdd(&cnt, local);
  __syncthreads();
  if (threadIdx.x == 0) *flag = (cnt > 2048) ? 1 : 0;
}

// ---------- canonicalize x -> bf16 ----------
__global__ __launch_bounds__(256) void cvt_x_k(const void* __restrict__ src,
                                               bf16* __restrict__ dst,
                                               const int* __restrict__ flag, int n) {
  const bool isbf = (*flag != 0);
  const int stride = gridDim.x * blockDim.x * 8;
  for (int idx = (blockIdx.x * blockDim.x + threadIdx.x) * 8; idx < n; idx += stride) {
    bf16x8 o;
    if (isbf) {
      bf16x8 v = *(const bf16x8*)((const bf16*)src + idx);
      #pragma unroll
      for (int j = 0; j < 8; ++j) o[j] = (bf16)scrub((float)v[j]);
    } else {
      const float* s = (const float*)src + idx;
      #pragma unroll
      for (int j = 0; j < 8; ++j) o[j] = (bf16)scrub(s[j]);
    }
    *(bf16x8*)&dst[idx] = o;
  }
}

// ---------- 4-way transpose+canonicalize: dstz[n][k] = srcz[k][n] ----------
__global__ __launch_bounds__(256) void wtrans_cvt4_k(const void* __restrict__ W0,
                                                     const void* __restrict__ W1,
                                                     const void* __restrict__ W2,
                                                     const void* __restrict__ W3,
                                                     bf16* __restrict__ dstBase,
                                                     const int* __restrict__ flag) {
  __shared__ bf16 t[32][33];
  const bool isbf = (*flag != 0);
  const int z = blockIdx.z;
  const void* src = (z == 0) ? W0 : (z == 1) ? W1 : (z == 2) ? W2 : W3;
  bf16* dst = dstBase + (size_t)z * D * D;
  const int bx = blockIdx.x * 32, by = blockIdx.y * 32;
  const int tx = threadIdx.x & 31, ty = threadIdx.x >> 5;
  for (int i = ty; i < 32; i += 8) {
    const size_t off = (size_t)(by + i) * D + bx + tx;
    const float v = isbf ? (float)((const bf16*)src)[off] : ((const float*)src)[off];
    t[i][tx] = (bf16)scrub(v);
  }
  __syncthreads();
  for (int i = ty; i < 32; i += 8)
    dst[(size_t)(bx + i) * D + by + tx] = t[tx][i];
}

// ---------- per-head V transpose: VT[bh][d][l] = V[(b,l)][h*64+d] ----------
__global__ __launch_bounds__(256) void vtrans_k(const bf16* __restrict__ V,
                                                bf16* __restrict__ VT) {
  __shared__ __align__(16) bf16 t[64 * 72];
  const int l0 = blockIdx.x * 64, bh = blockIdx.y;
  const int b = bh >> 4, h = bh & 15;
  const int tid = threadIdx.x;
  #pragma unroll
  for (int i = 0; i < 2; ++i) {
    const int o = tid * 8 + i * 2048;
    const int lrow = o >> 6, dcol = o & 63;
    *(bf16x8*)&t[lrow * 72 + dcol] =
        *(const bf16x8*)&V[(size_t)(b * L + l0 + lrow) * D + h * 64 + dcol];
  }
  __syncthreads();
  const int d = tid >> 2, lg = (tid & 3) * 16;
  bf16x8 o0, o1;
  #pragma unroll
  for (int j = 0; j < 8; ++j) o0[j] = t[(lg + j) * 72 + d];
  #pragma unroll
  for (int j = 0; j < 8; ++j) o1[j] = t[(lg + 8 + j) * 72 + d];
  bf16* dst = VT + ((size_t)bh * DH + d) * L + l0 + lg;
  *(bf16x8*)dst = o0;
  *(bf16x8*)(dst + 8) = o1;
}

// ---------- fused QKV GEMM: [Q|K|V] = x @ [WqT|WkT|WvT]^T + b ----------
// Bt is the stacked [3072][1024] weight; buffer selected by n0>>10 (uniform).
// Q epilogue folds the 1/sqrt(DH)=0.125 attention scale.
__global__ __launch_bounds__(256) void qkv_gemm_k(const bf16* __restrict__ A,
                                                  const bf16* __restrict__ Bt,
                                                  const void* __restrict__ bq,
                                                  const void* __restrict__ bk,
                                                  const void* __restrict__ bv,
                                                  bf16* __restrict__ Q,
                                                  bf16* __restrict__ Kk,
                                                  bf16* __restrict__ V,
                                                  const int* __restrict__ flag) {
  __shared__ __align__(16) bf16 As[128 * BKg];
  __shared__ __align__(16) bf16 Bs[128 * BKg];
  const bool isbf = (*flag != 0);
  const int m0 = blockIdx.x * 128, n0 = blockIdx.y * 128;
  const int buf = n0 >> 10, nloc = n0 & 1023;
  bf16* Cb = (buf == 0) ? Q : (buf == 1) ? Kk : V;
  const void* bias = (buf == 0) ? bq : (buf == 1) ? bk : bv;
  const float scale = (buf == 0) ? 0.125f : 1.0f;

  const int tid = threadIdx.x, wave = tid >> 6, lane = tid & 63;
  const int wr = wave >> 1, wc = wave & 1;
  const int quad = lane >> 4, l16 = lane & 15;
  const int srow = lane >> 3;
  const int scol = ((lane ^ srow) & 7) * 8;
  const int l7 = l16 & 7;
  const int s0 = ((quad ^ l7) * 8);
  const int s1 = s0 ^ 32;

  f32x4 acc[4][4] = {};

  for (int k0 = 0; k0 < GK; k0 += BKg) {
    for (int c = wave; c < 16; c += 4) {
      load_lds16(A  + (size_t)(m0 + c * 8 + srow) * GK + k0 + scol, &As[c * 512]);
      load_lds16(Bt + (size_t)(n0 + c * 8 + srow) * GK + k0 + scol, &Bs[c * 512]);
    }
    __syncthreads();
    #pragma unroll
    for (int kk = 0; kk < BKg; kk += 32) {
      const int sk = kk ? s1 : s0;
      bf16x8 af[4], bfr[4];
      #pragma unroll
      for (int i = 0; i < 4; ++i)
        af[i] = *(const bf16x8*)&As[(wr * 64 + i * 16 + l16) * BKg + sk];
      #pragma unroll
      for (int i = 0; i < 4; ++i)
        bfr[i] = *(const bf16x8*)&Bs[(wc * 64 + i * 16 + l16) * BKg + sk];
      #pragma unroll
      for (int mi = 0; mi < 4; ++mi)
        #pragma unroll
        for (int ni = 0; ni < 4; ++ni)
          acc[mi][ni] = mfma(af[mi], bfr[ni], acc[mi][ni]);
    }
    __syncthreads();
  }

  #pragma unroll
  for (int ni = 0; ni < 4; ++ni) {
    const int col = nloc + wc * 64 + ni * 16 + l16;
    const float bv2 = isbf ? (float)((const bf16*)bias)[col] : ((const float*)bias)[col];
    #pragma unroll
    for (int mi = 0; mi < 4; ++mi)
      #pragma unroll
      for (int r = 0; r < 4; ++r) {
        const int row = m0 + wr * 64 + mi * 16 + quad * 4 + r;
        Cb[(size_t)row * D + col] = (bf16)((acc[mi][ni][r] + bv2) * scale);
      }
  }
}

// ---------- final GEMM: out = attnO @ WoT^T + bo (dtype per flag) ----------
__global__ __launch_bounds__(256) void gemm_bt_k(const bf16* __restrict__ A,
                                                 const bf16* __restrict__ Bt,
                                                 const void* __restrict__ bias,
                                                 void* __restrict__ C,
                                                 const int* __restrict__ flag) {
  __shared__ __align__(16) bf16 As[128 * BKg];
  __shared__ __align__(16) bf16 Bs[128 * BKg];
  const bool isbf = (*flag != 0);
  const int m0 = blockIdx.x * 128, n0 = blockIdx.y * 128;
  const int tid = threadIdx.x, wave = tid >> 6, lane = tid & 63;
  const int wr = wave >> 1, wc = wave & 1;
  const int quad = lane >> 4, l16 = lane & 15;
  const int srow = lane >> 3;
  const int scol = ((lane ^ srow) & 7) * 8;
  const int l7 = l16 & 7;
  const int s0 = ((quad ^ l7) * 8);
  const int s1 = s0 ^ 32;

  f32x4 acc[4][4] = {};

  for (int k0 = 0; k0 < GK; k0 += BKg) {
    for (int c = wave; c < 16; c += 4) {
      load_lds16(A  + (size_t)(m0 + c * 8 + srow) * GK + k0 + scol, &As[c * 512]);
      load_lds16(Bt + (size_t)(n0 + c * 8 + srow) * GK + k0 + scol, &Bs[c * 512]);
    }
    __syncthreads();
    #pragma unroll
    for (int kk = 0; kk < BKg; kk += 32) {
      const int sk = kk ? s1 : s0;
      bf16x8 af[4], bfr[4];
      #pragma unroll
      for (int i = 0; i < 4; ++i)
        af[i] = *(const bf16x8*)&As[(wr * 64 + i * 16 + l16) * BKg + sk];
      #pragma unroll
      for (int i = 0; i < 4; ++i)
        bfr[i] = *(const bf16x8*)&Bs[(wc * 64 + i * 16 + l16) * BKg + sk];
      #pragma unroll
      for (int mi = 0; mi < 4; ++mi)
        #pragma unroll
        for (int ni = 0; ni < 4; ++ni)
          acc[mi][ni] = mfma(af[mi], bfr[ni], acc[mi][ni]);
    }
    __syncthreads();
  }

  bf16* Cb = (bf16*)C;
  float* Cf = (float*)C;
  #pragma unroll
  for (int ni = 0; ni < 4; ++ni) {
    const int col = n0 + wc * 64 + ni * 16 + l16;
    const float bv = isbf ? (float)((const bf16*)bias)[col] : ((const float*)bias)[col];
    #pragma unroll
    for (int mi = 0; mi < 4; ++mi)
      #pragma unroll
      for (int r = 0; r < 4; ++r) {
        const int row = m0 + wr * 64 + mi * 16 + quad * 4 + r;
        const float v = acc[mi][ni][r] + bv;
        if (isbf) Cb[(size_t)row * D + col] = (bf16)v;
        else      Cf[(size_t)row * D + col] = v;
      }
  }
}

// ---------- fused causal flash attention v4: S^T orientation ----------
// S^T = K·Q^T per 16-key block: C row=quad*4+r -> key, col=l16 -> q-row.
// Per-lane softmax state is a SCALAR (one q-row per lane). P written packed
// (b64) in [q][key] layout for the PV A-frag. Q pre-scaled by GEMM.
__global__ __launch_bounds__(256) void attn_k(bf16* QO,
                                              const bf16* __restrict__ K,
                                              const bf16* __restrict__ VT) {
  __shared__ __align__(16) bf16 Ks[64 * DH];       // swizzled [key][d]
  __shared__ __align__(16) bf16 Vt[DH * 64];       // swizzled [d][key]
  __shared__ __align__(16) bf16 Ps[4][16 * PST];   // per-wave P [q][key], padded

  const int bx = blockIdx.x;
  const int qt = (L / 64 - 1) - (bx >> 6);
  const int bh = bx & 63;
  const int b = bh >> 4, h = bh & 15;
  const int tid = threadIdx.x, wave = tid >> 6, lane = tid & 63;
  const int quad = lane >> 4, l16 = lane & 15;
  const int srow = lane >> 3;
  const int scol = ((lane ^ srow) & 7) * 8;
  const int l7 = l16 & 7;
  const int s0 = ((quad ^ l7) * 8);
  const int s1 = s0 ^ 32;

  bf16* Qb = QO + (size_t)b * L * D + h * DH;
  const bf16* Kb = K + (size_t)b * L * D + h * DH;
  const bf16* VTg = VT + (size_t)bh * DH * L;

  // Q B-frags (same register layout as old A-frags); scale already folded in
  const int qrow = qt * 64 + wave * 16 + l16;
  const bf16x8 qf0 = *(const bf16x8*)(Qb + (size_t)qrow * D + quad * 8);
  const bf16x8 qf1 = *(const bf16x8*)(Qb + (size_t)qrow * D + 32 + quad * 8);

  float m_run = -INFINITY, l_run = 0.f;   // state for q-row l16 (per lane)
  f32x4 o_acc[4] = {};                    // PV C-layout: row=quad*4+r -> q

  for (int kt = 0; kt <= qt; ++kt) {
    for (int c = wave; c < 8; c += 4) {
      load_lds16(Kb  + (size_t)(kt * 64 + c * 8 + srow) * D + scol, &Ks[c * 512]);
      load_lds16(VTg + (size_t)(c * 8 + srow) * L + kt * 64 + scol, &Vt[c * 512]);
    }
    __syncthreads();

    // S^T = K @ Q^T: A=K-frag, B=Q-frag. s[nb][r] = S[key=nb*16+quad*4+r][q=l16]
    f32x4 s[4];
    #pragma unroll
    for (int nb = 0; nb < 4; ++nb) {
      bf16x8 k0 = *(const bf16x8*)&Ks[(nb * 16 + l16) * DH + s0];
      bf16x8 k1 = *(const bf16x8*)&Ks[(nb * 16 + l16) * DH + s1];
      f32x4 a = {};
      a = mfma(k0, qf0, a);
      a = mfma(k1, qf1, a);
      s[nb] = a;
    }

    if (kt == qt) { // diagonal causal mask: key > qrow (both 64-tile local)
      const int qloc = wave * 16 + l16 + (qt - kt) * 64; // == wave*16+l16 here
      #pragma unroll
      for (int nb = 0; nb < 4; ++nb)
        #pragma unroll
        for (int r = 0; r < 4; ++r)
          if (nb * 16 + quad * 4 + r > qloc) s[nb][r] = -1e30f;
    }

    // online softmax, per-lane scalar state (q-row = l16)
    float mx = -INFINITY;
    #pragma unroll
    for (int nb = 0; nb < 4; ++nb)
      #pragma unroll
      for (int r = 0; r < 4; ++r) mx = fmaxf(mx, s[nb][r]);
    mx = fmaxf(mx, __shfl_xor(mx, 16, 64));
    mx = fmaxf(mx, __shfl_xor(mx, 32, 64));
    const float mn = fmaxf(m_run, mx);
    const float alpha = __expf(m_run - mn);
    m_run = mn;

    bf16* Pw = &Ps[wave][0];
    float sum = 0.f;
    #pragma unroll
    for (int nb = 0; nb < 4; ++nb) {
      bf16x4 pk;
      #pragma unroll
      for (int r = 0; r < 4; ++r) {
        const float p = __expf(s[nb][r] - mn);
        sum += p;
        pk[r] = (bf16)p;
      }
      *(bf16x4*)&Pw[l16 * PST + nb * 16 + quad * 4] = pk; // packed b64 write
    }
    sum += __shfl_xor(sum, 16, 64);
    sum += __shfl_xor(sum, 32, 64);
    l_run = l_run * alpha + sum;

    // redistribute alpha to o_acc rows (row quad*4+r <- lane quad*4+r)
    #pragma unroll
    for (int r = 0; r < 4; ++r) {
      const float ar = __shfl(alpha, quad * 4 + r, 64);
      #pragma unroll
      for (int db = 0; db < 4; ++db) o_acc[db][r] *= ar;
    }

    // O += P @ V  (A = P[q][k] from LDS, B = V^T[d][k] swizzled)
    bf16x8 p0 = *(const bf16x8*)&Pw[l16 * PST + quad * 8];
    bf16x8 p1 = *(const bf16x8*)&Pw[l16 * PST + 32 + quad * 8];
    #pragma unroll
    for (int db = 0; db < 4; ++db) {
      bf16x8 v0 = *(const bf16x8*)&Vt[(db * 16 + l16) * 64 + s0];
      bf16x8 v1 = *(const bf16x8*)&Vt[(db * 16 + l16) * 64 + s1];
      o_acc[db] = mfma(p0, v0, o_acc[db]);
      o_acc[db] = mfma(p1, v1, o_acc[db]);
    }
    __syncthreads(); // protect Ks/Vt before next tile's staging
  }

  #pragma unroll
  for (int r = 0; r < 4; ++r) {
    const float lr = __shfl(l_run, quad * 4 + r, 64);
    const float inv = 1.f / lr;
    const int row = qt * 64 + wave * 16 + quad * 4 + r;
    #pragma unroll
    for (int db = 0; db < 4; ++db)
      Qb[(size_t)row * D + db * 16 + l16] = (bf16)(o_acc[db][r] * inv);
  }
}

extern "C" void kernel_launch(void* const* d_in, const int* in_sizes, int n_in,
                              void* d_out, int out_size, void* d_ws, size_t ws_size,
                              hipStream_t stream) {
  const void* x  = d_in[0];
  const void* Wq = d_in[1];
  const void* bq = d_in[2];
  const void* Wk = d_in[3];
  const void* bk = d_in[4];
  const void* Wv = d_in[5];
  const void* bv = d_in[6];
  const void* Wo = d_in[7];
  const void* bo = d_in[8];
  // d_in[9] = causal mask, analytic

  int* flag = (int*)d_ws;
  char* p = (char*)d_ws + 4096;
  bf16* xc  = (bf16*)p;                 p += (size_t)BL * D * 2;
  bf16* WqT = (bf16*)p;                 p += (size_t)D * D * 2; // WqT/WkT/WvT/WoT
  bf16* WkT = (bf16*)p;                 p += (size_t)D * D * 2; // contiguous =
  bf16* WvT = (bf16*)p;                 p += (size_t)D * D * 2; // stacked [4096][1024]
  bf16* WoT = (bf16*)p;                 p += (size_t)D * D * 2;
  bf16* Qb  = (bf16*)p;                 p += (size_t)BL * D * 2; // O aliases Q
  bf16* Kb  = (bf16*)p;                 p += (size_t)BL * D * 2;
  bf16* Vb  = (bf16*)p;
  bf16* VTb = xc; // xc dead after QKV GEMM; reuse for V^T

  sniff_k<<<1, 64, 0, stream>>>((const unsigned short*)x, flag);

  cvt_x_k<<<1024, 256, 0, stream>>>(x, xc, flag, BL * D);
  wtrans_cvt4_k<<<dim3(32, 32, 4), 256, 0, stream>>>(Wq, Wk, Wv, Wo, WqT, flag);

  qkv_gemm_k<<<dim3(GM / 128, 3072 / 128), 256, 0, stream>>>(
      xc, WqT, bq, bk, bv, Qb, Kb, Vb, flag);

  vtrans_k<<<dim3(L / 64, B * H), 256, 0, stream>>>(Vb, VTb);

  attn_k<<<dim3((L / 64) * B * H), 256, 0, stream>>>(Qb, Kb, VTb);

  gemm_bt_k<<<dim3(GM / 128, D / 128), 256, 0, stream>>>(Qb, WoT, bo, d_out, flag);
}